// Round 2
// baseline (428.376 us; speedup 1.0000x reference)
//
#include <hip/hip_runtime.h>
#include <stdint.h>

typedef unsigned short bf16;
typedef __attribute__((ext_vector_type(8))) short short8;
typedef __attribute__((ext_vector_type(4))) float f32x4;

#define MFMA16(a, b, c) __builtin_amdgcn_mfma_f32_16x16x32_bf16((a), (b), (c), 0, 0, 0)

__device__ __forceinline__ bf16 f2bf(float f) {
    unsigned u = __float_as_uint(f);
    u += 0x7fffu + ((u >> 16) & 1u);
    return (bf16)(u >> 16);
}
__device__ __forceinline__ float bf2f(bf16 s) { return __uint_as_float(((unsigned)s) << 16); }
__device__ __forceinline__ unsigned pack2(float a, float b) {
    return ((unsigned)f2bf(a)) | (((unsigned)f2bf(b)) << 16);
}
__device__ __forceinline__ float sigmoidf_(float x) { return 1.f / (1.f + __expf(-x)); }

__device__ __forceinline__ void gload_lds16(const void* g, void* lds) {
    auto gp = (const __attribute__((address_space(1))) unsigned int*)(uintptr_t)g;
    auto lp = (__attribute__((address_space(3))) unsigned int*)(uintptr_t)lds;
    __builtin_amdgcn_global_load_lds(gp, lp, 16, 0, 0);
}

// ---------------- K0: weight fp32 -> bf16 ----------------
__global__ __launch_bounds__(256) void k_wconv(const float* __restrict__ aw,
                                               const float* __restrict__ agw,
                                               const float* __restrict__ gw,
                                               const float* __restrict__ ow,
                                               bf16* __restrict__ wbf,
                                               bf16* __restrict__ owbf) {
    int i = blockIdx.x * 256 + threadIdx.x;  // grid 256 -> 65536
    int m = i >> 14, k = i & 16383;
    const float* s = (m == 0) ? aw : (m == 1) ? agw : (m == 2) ? gw : ow;
    float v = s[k];
    if (m < 3) wbf[i] = f2bf(v); else owbf[k] = f2bf(v);
}

// ---------------- K1: LN(z) + 3 projections (conflict-free LDS, reg A-frags) ----------------
__global__ __launch_bounds__(256) void k_ln_proj(const float* __restrict__ z,
                                                 const float* __restrict__ ng,
                                                 const float* __restrict__ nb,
                                                 const float* __restrict__ ab,
                                                 const float* __restrict__ agb,
                                                 const float* __restrict__ gbv,
                                                 const bf16* __restrict__ wbf,
                                                 bf16* __restrict__ a_t,
                                                 bf16* __restrict__ gbuf) {
    __shared__ bf16 zn_s[64 * 128];   // XOR-swizzled chunks; reused as gbuf stage (64x128)
    __shared__ bf16 w_s[128 * 128];   // XOR-swizzled chunks; reused as a_t stage (128x72)

    const int t = threadIdx.x;
    const int r0 = blockIdx.x * 64;
    const int lane = t & 63, w = t >> 6;
    const int lr = lane & 15, quad = lane >> 4;
    const int row = w * 16 + lr;  // local row 0..63; this lane owns quarter `quad` of it

    // ---- LN: one lane per (row, quarter) ----
    float x[32];
    {
        const float* zp = z + (size_t)(r0 + row) * 128 + quad * 32;
        float s = 0.f, ss = 0.f;
#pragma unroll
        for (int i = 0; i < 8; ++i) {
            float4 v = ((const float4*)zp)[i];
            x[4 * i + 0] = v.x; x[4 * i + 1] = v.y; x[4 * i + 2] = v.z; x[4 * i + 3] = v.w;
        }
#pragma unroll
        for (int i = 0; i < 32; ++i) { s += x[i]; ss += x[i] * x[i]; }
        s += __shfl_xor(s, 16); ss += __shfl_xor(ss, 16);
        s += __shfl_xor(s, 32); ss += __shfl_xor(ss, 32);
        float mean = s * (1.f / 128.f);
        float var = ss * (1.f / 128.f) - mean * mean;
        float rstd = rsqrtf(var + 1e-5f);
#pragma unroll
        for (int i = 0; i < 8; ++i) {
            float4 g4 = ((const float4*)(ng + quad * 32))[i];
            float4 b4 = ((const float4*)(nb + quad * 32))[i];
            x[4 * i + 0] = (x[4 * i + 0] - mean) * rstd * g4.x + b4.x;
            x[4 * i + 1] = (x[4 * i + 1] - mean) * rstd * g4.y + b4.y;
            x[4 * i + 2] = (x[4 * i + 2] - mean) * rstd * g4.z + b4.z;
            x[4 * i + 3] = (x[4 * i + 3] - mean) * rstd * g4.w + b4.w;
        }
    }
    // pack + swizzled vector write of zn (conflict-free b128)
    {
        unsigned zd[16];
#pragma unroll
        for (int j = 0; j < 16; ++j) zd[j] = pack2(x[2 * j], x[2 * j + 1]);
#pragma unroll
        for (int i = 0; i < 4; ++i) {
            int c = quad * 4 + i;
            int pos = (c & 8) | ((c & 7) ^ (row & 7));
            uint4 d; d.x = zd[4 * i]; d.y = zd[4 * i + 1]; d.z = zd[4 * i + 2]; d.w = zd[4 * i + 3];
            *(uint4*)&zn_s[row * 128 + pos * 8] = d;
        }
    }

    auto stage_w = [&](int mat) {
        const bf16* src = wbf + mat * 16384;
#pragma unroll
        for (int i = 0; i < 8; ++i) {
            int idx = i * 256 + t;  // 0..2047
            int rw = idx >> 4, c = idx & 15;
            int csrc = (c & 8) | ((c & 7) ^ (rw & 7));
            gload_lds16(src + rw * 128 + csrc * 8, w_s + idx * 8);
        }
    };

    stage_w(0);
    __syncthreads();  // A: zn_s + w0 ready

    // A-fragments in registers, reused by all 3 GEMMs
    short8 af[4];
#pragma unroll
    for (int kk = 0; kk < 4; ++kk) {
        int c = kk * 4 + quad;
        int pos = (c & 8) | ((c & 7) ^ (row & 7));
        af[kk] = *(const short8*)&zn_s[row * 128 + pos * 8];
    }

    auto gemm = [&](f32x4* acc) {
#pragma unroll
        for (int kk = 0; kk < 4; ++kk) {
            int c = kk * 4 + quad;
#pragma unroll
            for (int nt = 0; nt < 8; ++nt) {
                int rw = nt * 16 + lr;
                int pos = (c & 8) | ((c & 7) ^ (rw & 7));
                short8 bfr = *(const short8*)&w_s[rw * 128 + pos * 8];
                acc[nt] = MFMA16(af[kk], bfr, acc[nt]);
            }
        }
    };

    f32x4 zero4 = {0.f, 0.f, 0.f, 0.f};
    f32x4 acc_a[8], acc_b[8];
#pragma unroll
    for (int nt = 0; nt < 8; ++nt) { acc_a[nt] = zero4; acc_b[nt] = zero4; }

    gemm(acc_a);      // proj_a (w0)
    __syncthreads();  // B: w0 reads done
    stage_w(1);
    __syncthreads();  // C: w1 ready
    gemm(acc_b);      // proj_ag
    __syncthreads();  // D: w1 reads done, w_s reusable

    // epilogue a: transposed stage in w_s, [c][72] pad, packed b64 (conflict-free)
    bf16* st_a = w_s;
#pragma unroll
    for (int nt = 0; nt < 8; ++nt) {
        int c = nt * 16 + lr;
        float abv = ab[c], agbv = agb[c];
        float v0 = (acc_a[nt][0] + abv) * sigmoidf_(acc_b[nt][0] + agbv);
        float v1 = (acc_a[nt][1] + abv) * sigmoidf_(acc_b[nt][1] + agbv);
        float v2 = (acc_a[nt][2] + abv) * sigmoidf_(acc_b[nt][2] + agbv);
        float v3 = (acc_a[nt][3] + abv) * sigmoidf_(acc_b[nt][3] + agbv);
        uint2 d; d.x = pack2(v0, v1); d.y = pack2(v2, v3);
        *(uint2*)&st_a[c * 72 + w * 16 + quad * 4] = d;
    }
    __syncthreads();  // E: stage visible
#pragma unroll
    for (int i = 0; i < 4; ++i) {
        int idx = i * 256 + t;  // 0..1023
        int c = idx >> 3, part = idx & 7;
        *(uint4*)(a_t + (size_t)c * 262144 + r0 + part * 8) = *(const uint4*)&st_a[c * 72 + part * 8];
    }
    __syncthreads();  // F: st_a reads done before w2 overwrite
    stage_w(2);
    __syncthreads();  // G: w2 ready
#pragma unroll
    for (int nt = 0; nt < 8; ++nt) acc_a[nt] = zero4;
    gemm(acc_a);      // proj_g

    // epilogue g: row-major stage in zn_s (free: af already in regs)
    bf16* st_g = zn_s;
#pragma unroll
    for (int nt = 0; nt < 8; ++nt) {
        int c = nt * 16 + lr;
        float gb0 = gbv[c];
#pragma unroll
        for (int r = 0; r < 4; ++r)
            st_g[(w * 16 + quad * 4 + r) * 128 + c] = f2bf(sigmoidf_(acc_a[nt][r] + gb0));
    }
    __syncthreads();  // H
#pragma unroll
    for (int i = 0; i < 4; ++i) {
        int idx = i * 256 + t;
        int rr = idx >> 4, part = idx & 15;
        *(uint4*)(gbuf + (size_t)(r0 + rr) * 128 + part * 8) = *(const uint4*)&st_g[rr * 128 + part * 8];
    }
}

// ---------------- K2: symmetric einsum O_c = A_c A_c^T, dbuf prefetch ----------------
__global__ __launch_bounds__(256) void k_einsum(const bf16* __restrict__ a_t,
                                                bf16* __restrict__ o_t) {
    __shared__ bf16 smem[32768];  // A0 B0 A1 B1 (8192 el each); epilogue reuses [0,17408) as padded Cs

    const int t = threadIdx.x;
    const int bx = blockIdx.x;
    const int c = bx / 10;
    const int pi = bx - c * 10;
    const int ti = (pi < 4) ? 0 : (pi < 7) ? 1 : (pi < 9) ? 2 : 3;
    const int tj = pi - ((pi < 4) ? 0 : (pi < 7) ? 3 : (pi < 9) ? 5 : 6);
    const bool diag = (ti == tj);
    const int i0 = ti * 128, j0 = tj * 128;
    const size_t cbase = (size_t)c * 262144;
    const bf16* Ac = a_t + cbase;

    const int lane = t & 63, w = t >> 6;
    const int lr = lane & 15, quad = lane >> 4;
    const int wi = w >> 1, wj = w & 1;

    auto stage = [&](int kb, int buf) {
        bf16* As = smem + buf * 16384;
        bf16* Bs = As + 8192;
#pragma unroll
        for (int q = 0; q < 4; ++q) {
            int t16 = (w << 8) + (q << 6) + lane;
            int rw = t16 >> 3, cb = t16 & 7;
            int gcol = (kb << 6) + ((cb ^ (rw & 7)) << 3);
            gload_lds16(Ac + (size_t)(i0 + rw) * 512 + gcol, As + t16 * 8);
            if (!diag) gload_lds16(Ac + (size_t)(j0 + rw) * 512 + gcol, Bs + t16 * 8);
        }
    };

    f32x4 zero4 = {0.f, 0.f, 0.f, 0.f};
    f32x4 acc[4][4];
#pragma unroll
    for (int mt = 0; mt < 4; ++mt)
#pragma unroll
        for (int nt = 0; nt < 4; ++nt) acc[mt][nt] = zero4;

    stage(0, 0);
    for (int kb = 0; kb < 8; ++kb) {
        __syncthreads();                       // drains this iter's buffer loads (prefetched last iter)
        if (kb < 7) stage(kb + 1, (kb + 1) & 1);  // prefetch overlaps MFMA phase below
        const bf16* As = smem + (kb & 1) * 16384;
        const bf16* Bs = diag ? As : As + 8192;
#pragma unroll
        for (int kk8 = 0; kk8 < 8; kk8 += 4) {
            short8 af[4], bfr[4];
#pragma unroll
            for (int mt = 0; mt < 4; ++mt)
                af[mt] = *(const short8*)&As[(wi * 64 + mt * 16 + lr) * 64 + (((kk8 + quad) ^ (lr & 7)) << 3)];
#pragma unroll
            for (int nt = 0; nt < 4; ++nt)
                bfr[nt] = *(const short8*)&Bs[(wj * 64 + nt * 16 + lr) * 64 + (((kk8 + quad) ^ (lr & 7)) << 3)];
#pragma unroll
            for (int mt = 0; mt < 4; ++mt)
#pragma unroll
                for (int nt = 0; nt < 4; ++nt)
                    acc[mt][nt] = MFMA16(af[mt], bfr[nt], acc[mt][nt]);
        }
    }

    __syncthreads();
    bf16* Cs = smem;  // [128][136] padded
    bf16* Oc = o_t + cbase;
#pragma unroll
    for (int mt = 0; mt < 4; ++mt)
#pragma unroll
        for (int nt = 0; nt < 4; ++nt)
#pragma unroll
            for (int r = 0; r < 4; ++r) {
                int il = wi * 64 + mt * 16 + quad * 4 + r;
                int jl = wj * 64 + nt * 16 + lr;
                Cs[il * 136 + jl] = f2bf(acc[mt][nt][r]);
            }
    __syncthreads();
#pragma unroll
    for (int i = 0; i < 8; ++i) {
        int idx = (i << 8) + t;
        int rw = idx >> 4, part = idx & 15;
        *(uint4*)(Oc + (size_t)(i0 + rw) * 512 + j0 + part * 8) = *(const uint4*)&Cs[rw * 136 + part * 8];
    }
    if (!diag) {
        __syncthreads();
#pragma unroll
        for (int mt = 0; mt < 4; ++mt)
#pragma unroll
            for (int nt = 0; nt < 4; ++nt)
#pragma unroll
                for (int r = 0; r < 4; ++r) {
                    int il = wi * 64 + mt * 16 + quad * 4 + r;
                    int jl = wj * 64 + nt * 16 + lr;
                    Cs[jl * 136 + il] = f2bf(acc[mt][nt][r]);
                }
        __syncthreads();
#pragma unroll
        for (int i = 0; i < 8; ++i) {
            int idx = (i << 8) + t;
            int rw = idx >> 4, part = idx & 15;
            *(uint4*)(Oc + (size_t)(j0 + rw) * 512 + i0 + part * 8) = *(const uint4*)&Cs[rw * 136 + part * 8];
        }
    }
}

// ---------------- K3: LN over c + out-projection + gate ----------------
__global__ __launch_bounds__(256) void k_out(const bf16* __restrict__ o_t,
                                             const bf16* __restrict__ gbuf,
                                             const float* __restrict__ og,
                                             const float* __restrict__ ob,
                                             const bf16* __restrict__ owbf,
                                             const float* __restrict__ obias,
                                             float* __restrict__ out) {
    __shared__ bf16 pool[128 * 136];  // ot_s [128c][136p-pad] overlays n_s [128p][136c-pad]
    __shared__ float og_s[128], ob_s[128], obi_s[128];

    const int t = threadIdx.x;
    const int p0 = blockIdx.x * 128;
    if (t < 128) { og_s[t] = og[t]; ob_s[t] = ob[t]; obi_s[t] = obias[t]; }

#pragma unroll
    for (int i = 0; i < 8; ++i) {
        int idx = (i << 8) + t;
        int c = idx >> 4, part = idx & 15;
        *(uint4*)&pool[c * 136 + part * 8] = *(const uint4*)(o_t + (size_t)c * 262144 + p0 + part * 8);
    }
    __syncthreads();

    // LN over c per column; 2 lanes per column (2-way same-dword: free)
    {
        int col = t >> 1, h = t & 1;
        float xv[64];
        float s = 0.f, ss = 0.f;
#pragma unroll
        for (int k = 0; k < 64; ++k) {
            float x = bf2f(pool[(h * 64 + k) * 136 + col]);
            xv[k] = x; s += x; ss += x * x;
        }
        s += __shfl_xor(s, 1); ss += __shfl_xor(ss, 1);
        float mean = s * (1.f / 128.f);
        float var = ss * (1.f / 128.f) - mean * mean;
        float rstd = rsqrtf(var + 1e-5f);
        __syncthreads();  // all pool reads complete before overlay write
#pragma unroll
        for (int k = 0; k < 64; ++k) {
            int cc = h * 64 + k;
            pool[col * 136 + cc] = f2bf((xv[k] - mean) * rstd * og_s[cc] + ob_s[cc]);
        }
    }
    __syncthreads();

    const int lane = t & 63, w = t >> 6;
    const int lr = lane & 15, quad = lane >> 4;
    f32x4 zero4 = {0.f, 0.f, 0.f, 0.f};
    f32x4 acc[2][8];
#pragma unroll
    for (int mt = 0; mt < 2; ++mt)
#pragma unroll
        for (int nt = 0; nt < 8; ++nt) acc[mt][nt] = zero4;

#pragma unroll
    for (int kk = 0; kk < 4; ++kk) {
        short8 af[2];
#pragma unroll
        for (int mt = 0; mt < 2; ++mt)
            af[mt] = *(const short8*)&pool[(w * 32 + mt * 16 + lr) * 136 + kk * 32 + quad * 8];
#pragma unroll
        for (int nt = 0; nt < 8; ++nt) {
            short8 bfr = *(const short8*)(owbf + (nt * 16 + lr) * 128 + kk * 32 + quad * 8);
            acc[0][nt] = MFMA16(af[0], bfr, acc[0][nt]);
            acc[1][nt] = MFMA16(af[1], bfr, acc[1][nt]);
        }
    }

#pragma unroll
    for (int mt = 0; mt < 2; ++mt)
#pragma unroll
        for (int nt = 0; nt < 8; ++nt) {
            int zd = nt * 16 + lr;
            float bias = obi_s[zd];
#pragma unroll
            for (int r = 0; r < 4; ++r) {
                int m = w * 32 + mt * 16 + quad * 4 + r;
                size_t off = (size_t)(p0 + m) * 128 + zd;
                out[off] = (acc[mt][nt][r] + bias) * bf2f(gbuf[off]);
            }
        }
}

extern "C" void kernel_launch(void* const* d_in, const int* in_sizes, int n_in,
                              void* d_out, int out_size, void* d_ws, size_t ws_size,
                              hipStream_t stream) {
    (void)in_sizes; (void)n_in; (void)out_size; (void)ws_size;
    const float* z   = (const float*)d_in[0];
    const float* ng  = (const float*)d_in[1];
    const float* nb  = (const float*)d_in[2];
    const float* aw  = (const float*)d_in[3];
    const float* ab  = (const float*)d_in[4];
    const float* agw = (const float*)d_in[5];
    const float* agb = (const float*)d_in[6];
    const float* ong = (const float*)d_in[7];
    const float* onb = (const float*)d_in[8];
    const float* ow  = (const float*)d_in[9];
    const float* obi = (const float*)d_in[10];
    const float* gw  = (const float*)d_in[11];
    const float* gbb = (const float*)d_in[12];

    char* ws = (char*)d_ws;
    bf16* wbf  = (bf16*)(ws);                          // 3*16384 bf16
    bf16* owbf = (bf16*)(ws + 98304);
    bf16* a_t  = (bf16*)(ws + 131072);                 // 64 MiB
    bf16* gbuf = (bf16*)(ws + 131072 + 67108864);      // 64 MiB
    bf16* o_t  = (bf16*)(ws + 131072 + 2 * 67108864);  // 64 MiB

    k_wconv<<<256, 256, 0, stream>>>(aw, agw, gw, ow, wbf, owbf);
    k_ln_proj<<<4096, 256, 0, stream>>>(z, ng, nb, ab, agb, gbb, wbf, a_t, gbuf);
    k_einsum<<<1280, 256, 0, stream>>>(a_t, o_t);
    k_out<<<2048, 256, 0, stream>>>(o_t, gbuf, ong, onb, owbf, obi, (float*)d_out);
}